// Round 1
// 534.717 us; speedup vs baseline: 1.1052x; 1.1052x over previous
//
#include <hip/hip_runtime.h>
#include <stdint.h>

// RzLinear: out[M,N] = x[M,K] @ W[K,N] + bias, W[k,n] = table[((k*r3+n*r2+r1)%P)%H]
// P is a compile-time prime; H = 2^20 so %H is a mask.
// Phase 1: build Wt[N,K] bf16 + Xb[M,K] bf16 in ws.
// Phase 2: 256x256 deep-pipelined MFMA GEMM (ring-of-4 LDS K-step buffers,
//          counted vmcnt, swizzled LDS, setprio) — 8-phase-style schedule.

#define P_CONST 56598313u
#define HASH_MASK 0xFFFFFu
#define M_DIM 8192
#define N_DIM 4096
#define K_DIM 4096
#define BK 32
#define KSTEPS (K_DIM / BK)  // 128

typedef __attribute__((ext_vector_type(8))) short bf16x8;
typedef __attribute__((ext_vector_type(4))) float f32x4;

__device__ __forceinline__ unsigned short f2bf(float f) {
    unsigned int u = __float_as_uint(f);
    return (unsigned short)((u + 0x7FFFu + ((u >> 16) & 1u)) >> 16);  // RNE
}

struct RN { unsigned long long r1, r2, r3; };

// random_numbers = [P, r1, r2, r3]; reference dtype is int64 but hedge for int32.
__device__ __forceinline__ RN decode_rn(const void* rn_raw) {
    RN o;
    const long long* rn64 = (const long long*)rn_raw;
    if (rn64[0] == 56598313LL) {
        o.r1 = (unsigned long long)rn64[1];
        o.r2 = (unsigned long long)rn64[2];
        o.r3 = (unsigned long long)rn64[3];
    } else {
        const int* rn32 = (const int*)rn_raw;
        o.r1 = (unsigned long long)(unsigned int)rn32[1];
        o.r2 = (unsigned long long)(unsigned int)rn32[2];
        o.r3 = (unsigned long long)(unsigned int)rn32[3];
    }
    return o;
}

// direct global->LDS, 16B per lane (wave-uniform LDS base + lane*16)
__device__ __forceinline__ void load16(const void* g, void* l) {
    __builtin_amdgcn_global_load_lds(
        (const __attribute__((address_space(1))) void*)g,
        (__attribute__((address_space(3))) void*)l,
        16, 0, 0);
}

// ---------------- Phase 1a: Wt[n][k] = bf16(table[hash(k,n)]) ----------------
__global__ __launch_bounds__(256) void build_wt(const float* __restrict__ table,
                                                const void* __restrict__ rn_raw,
                                                unsigned short* __restrict__ Wt) {
    RN rn = decode_rn(rn_raw);
    const unsigned int stepu = (unsigned int)(rn.r3 % P_CONST);
    const unsigned int n = blockIdx.x;
    const unsigned long long base =
        ((unsigned long long)n * rn.r2 + rn.r1) % P_CONST;
    const int t = threadIdx.x;
#pragma unroll
    for (int e = 0; e < 2; ++e) {
        const int k0 = (t + e * 256) * 8;
        unsigned int cur =
            (unsigned int)((base + (unsigned long long)k0 * stepu) % P_CONST);
        union { unsigned short s[8]; uint4 v; } o;
#pragma unroll
        for (int i = 0; i < 8; ++i) {
            o.s[i] = f2bf(table[cur & HASH_MASK]);
            cur += stepu;
            if (cur >= P_CONST) cur -= P_CONST;
        }
        *(uint4*)(Wt + (size_t)n * K_DIM + k0) = o.v;
    }
}

// ---------------- Phase 1b: Xb = bf16(x) ----------------
__global__ __launch_bounds__(256) void cvt_x(const float* __restrict__ x,
                                             unsigned short* __restrict__ xb) {
    const size_t i8 = ((size_t)blockIdx.x * 256 + threadIdx.x) * 8;
    const float4 a = *(const float4*)(x + i8);
    const float4 b = *(const float4*)(x + i8 + 4);
    union { unsigned short s[8]; uint4 v; } o;
    o.s[0] = f2bf(a.x); o.s[1] = f2bf(a.y); o.s[2] = f2bf(a.z); o.s[3] = f2bf(a.w);
    o.s[4] = f2bf(b.x); o.s[5] = f2bf(b.y); o.s[6] = f2bf(b.z); o.s[7] = f2bf(b.w);
    *(uint4*)(xb + i8) = o.v;
}

// ---------------- Phase 2: 256x256 pipelined GEMM ----------------
// A: [M][K] bf16 row-major, Bt: [N][K] bf16 row-major.
// 8 waves (2 M x 4 N), per-wave 128x64 C-tile, BK=32, ring of 4 K-step buffers.
// Staging runs 3 steps ahead; vmcnt(8) per step (2 steps in flight, never 0).
// LDS swizzle: involution p ^= ((p>>3)&0x30) applied to the GLOBAL source of
// global_load_lds (LDS dest stays linear) and to the ds_read address.
__global__ __launch_bounds__(512, 2) void gemm_bt8(
    const unsigned short* __restrict__ A,
    const unsigned short* __restrict__ Bt,
    const float* __restrict__ bias,
    float* __restrict__ C) {
    __shared__ __align__(16) unsigned short lA[4][256 * BK];  // 4 x 16 KiB
    __shared__ __align__(16) unsigned short lB[4][256 * BK];  // 4 x 16 KiB

    const int t = threadIdx.x;
    // bijective XCD swizzle: 512 blocks = 8 XCDs x 64
    const int bid0 = blockIdx.x;
    const int sb = (bid0 & 7) * 64 + (bid0 >> 3);
    const int m0 = (sb >> 4) * 256;  // 32 m-tiles
    const int n0 = (sb & 15) * 256;  // 16 n-tiles

    const int lane = t & 63;
    const int wid = t >> 6;
    const int wr = wid >> 2;  // 0..1 -> C rows wr*128..+127
    const int wc = wid & 3;   // 0..3 -> C cols wc*64..+63
    const int lm = lane & 15;
    const int q = lane >> 4;  // 0..3 (16B k-slot)
    // swizzled 16B slot within a 64B LDS row (2-way aliasing only = free)
    const int qswz = (q ^ ((lm >> 1) & 3)) << 4;

    // staging geometry: thread t owns LDS bytes p0=t*16 and p1=p0+8192 of each
    // 16 KiB tile; the global source is pre-swizzled so reads can be swizzled.
    const int p0 = t * 16;
    const int p1 = p0 + 8192;
    const int l0 = p0 ^ ((p0 >> 3) & 0x30);
    const int l1 = p1 ^ ((p1 >> 3) & 0x30);
    const int r0 = l0 >> 6, c0 = (l0 & 63) >> 1;  // row 0..127, col (elems)
    const int r1 = l1 >> 6, c1 = (l1 & 63) >> 1;  // row 128..255

    const unsigned short* Abase = A + (size_t)m0 * K_DIM;
    const unsigned short* Bbase = Bt + (size_t)n0 * K_DIM;

    f32x4 acc[8][4] = {};

#define STAGE_A(KS) do { const int b__ = (KS) & 3;                              \
    load16(Abase + (size_t)r0 * K_DIM + (KS) * BK + c0, (char*)&lA[b__][0] + p0);\
    load16(Abase + (size_t)r1 * K_DIM + (KS) * BK + c1, (char*)&lA[b__][0] + p1);\
} while (0)
#define STAGE_B(KS) do { const int b__ = (KS) & 3;                              \
    load16(Bbase + (size_t)r0 * K_DIM + (KS) * BK + c0, (char*)&lB[b__][0] + p0);\
    load16(Bbase + (size_t)r1 * K_DIM + (KS) * BK + c1, (char*)&lB[b__][0] + p1);\
} while (0)

    // Per step: top barrier (own vmcnt + barrier => whole tile landed).
    // phase0: read 4 A-frags + 4 B-frags, issue next A stage, 16 MFMA.
    // phase1: read 4 A-frags, issue next B stage, 16 MFMA.
    // WAR on ring buffer is safe: issuing wave passed the top barrier, which is
    // after every wave's lgkmcnt(0) of the step that last read that buffer.
#define STEP_BODY(KS, STG) do {                                                 \
    __builtin_amdgcn_s_barrier();                                               \
    asm volatile("" ::: "memory");                                              \
    const char* bufA = (const char*)&lA[(KS) & 3][0];                           \
    const char* bufB = (const char*)&lB[(KS) & 3][0];                           \
    bf16x8 af[4], bfr[4];                                                       \
    _Pragma("unroll")                                                           \
    for (int i = 0; i < 4; ++i)                                                 \
        af[i] = *(const bf16x8*)(bufA + (((wr * 128 + i * 16 + lm) << 6) | qswz));\
    _Pragma("unroll")                                                           \
    for (int j = 0; j < 4; ++j)                                                 \
        bfr[j] = *(const bf16x8*)(bufB + (((wc * 64 + j * 16 + lm) << 6) | qswz));\
    if (STG) STAGE_A((KS) + 3);                                                 \
    asm volatile("s_waitcnt lgkmcnt(0)" ::: "memory");                          \
    __builtin_amdgcn_sched_barrier(0);                                          \
    __builtin_amdgcn_s_setprio(1);                                              \
    _Pragma("unroll")                                                           \
    for (int i = 0; i < 4; ++i)                                                 \
        _Pragma("unroll")                                                       \
        for (int j = 0; j < 4; ++j)                                             \
            acc[i][j] = __builtin_amdgcn_mfma_f32_16x16x32_bf16(                \
                af[i], bfr[j], acc[i][j], 0, 0, 0);                             \
    __builtin_amdgcn_s_setprio(0);                                              \
    __builtin_amdgcn_s_barrier();                                               \
    asm volatile("" ::: "memory");                                              \
    _Pragma("unroll")                                                           \
    for (int i = 0; i < 4; ++i)                                                 \
        af[i] = *(const bf16x8*)(bufA + (((wr * 128 + 64 + i * 16 + lm) << 6) | qswz));\
    if (STG) STAGE_B((KS) + 3);                                                 \
    asm volatile("s_waitcnt lgkmcnt(0)" ::: "memory");                          \
    __builtin_amdgcn_sched_barrier(0);                                          \
    __builtin_amdgcn_s_setprio(1);                                              \
    _Pragma("unroll")                                                           \
    for (int i = 0; i < 4; ++i)                                                 \
        _Pragma("unroll")                                                       \
        for (int j = 0; j < 4; ++j)                                             \
            acc[i + 4][j] = __builtin_amdgcn_mfma_f32_16x16x32_bf16(            \
                af[i], bfr[j], acc[i + 4][j], 0, 0, 0);                         \
    __builtin_amdgcn_s_setprio(0);                                              \
} while (0)

    // prologue: stage steps 0,1,2 (12 loads/thread in flight)
    STAGE_A(0); STAGE_B(0);
    STAGE_A(1); STAGE_B(1);
    STAGE_A(2); STAGE_B(2);

#pragma unroll 1
    for (int ks = 0; ks < KSTEPS - 2; ++ks) {
        // retire step ks's 4 loads; steps ks+1, ks+2 (8 loads) stay in flight
        asm volatile("s_waitcnt vmcnt(8)" ::: "memory");
        STEP_BODY(ks, (ks < KSTEPS - 3));
    }
    asm volatile("s_waitcnt vmcnt(4)" ::: "memory");
    STEP_BODY(KSTEPS - 2, false);
    asm volatile("s_waitcnt vmcnt(0)" ::: "memory");
    STEP_BODY(KSTEPS - 1, false);

#undef STEP_BODY
#undef STAGE_A
#undef STAGE_B

    // epilogue: C/D layout col=lane&15, row=(lane>>4)*4+reg
#pragma unroll
    for (int j = 0; j < 4; ++j) {
        const int col = n0 + wc * 64 + j * 16 + lm;
        const float bv = bias[col];
#pragma unroll
        for (int i = 0; i < 8; ++i) {
            const int row = m0 + wr * 128 + i * 16 + q * 4;
#pragma unroll
            for (int r = 0; r < 4; ++r)
                C[(size_t)(row + r) * N_DIM + col] = acc[i][j][r] + bv;
        }
    }
}

// ---------------- Fallback: fused gather GEMM, zero workspace ----------------
__global__ __launch_bounds__(256) void gemm_fused(const float* __restrict__ X,
                                                  const float* __restrict__ table,
                                                  const void* __restrict__ rn_raw,
                                                  const float* __restrict__ bias,
                                                  float* __restrict__ C) {
    RN rn = decode_rn(rn_raw);
    const unsigned int stepu = (unsigned int)(rn.r3 % P_CONST);
    const unsigned int step32 =
        (unsigned int)(((unsigned long long)stepu * 32ull) % P_CONST);

    __shared__ __align__(16) unsigned short lA[128 * 32];
    __shared__ __align__(16) unsigned short lB[128 * 32];
    const int t = threadIdx.x;
    const int m0 = blockIdx.y * 128;
    const int n0 = blockIdx.x * 128;
    const int lane = t & 63;
    const int w = t >> 6;
    const int wr = w >> 1, wc = w & 1;
    const int lm = lane & 15, q = lane >> 4;

    unsigned int curB[2];
    int rowB[2], colB[2];
#pragma unroll
    for (int e = 0; e < 2; ++e) {
        const int c = t + e * 256;
        rowB[e] = c >> 2;
        colB[e] = (c & 3) * 8;
        const unsigned long long base =
            ((unsigned long long)(n0 + rowB[e]) * rn.r2 + rn.r1) % P_CONST;
        curB[e] =
            (unsigned int)((base + (unsigned long long)colB[e] * stepu) % P_CONST);
    }

    f32x4 acc[4][4] = {};

    for (int k0 = 0; k0 < K_DIM; k0 += 32) {
#pragma unroll
        for (int c = t; c < 1024; c += 256) {
            const int row = c >> 3, col = (c & 7) * 4;
            const float4 v =
                *(const float4*)(X + (size_t)(m0 + row) * K_DIM + k0 + col);
            ushort4 o;
            o.x = f2bf(v.x); o.y = f2bf(v.y); o.z = f2bf(v.z); o.w = f2bf(v.w);
            *(ushort4*)&lA[row * 32 + col] = o;
        }
#pragma unroll
        for (int e = 0; e < 2; ++e) {
            unsigned int cur = curB[e];
            union { unsigned short s[8]; uint4 v; } o;
#pragma unroll
            for (int i = 0; i < 8; ++i) {
                o.s[i] = f2bf(table[cur & HASH_MASK]);
                cur += stepu;
                if (cur >= P_CONST) cur -= P_CONST;
            }
            curB[e] += step32;
            if (curB[e] >= P_CONST) curB[e] -= P_CONST;
            *(uint4*)&lB[rowB[e] * 32 + colB[e]] = o.v;
        }
        __syncthreads();

        bf16x8 af[4], bfr[4];
#pragma unroll
        for (int i = 0; i < 4; ++i)
            af[i] = *(const bf16x8*)&lA[(wr * 64 + i * 16 + lm) * 32 + q * 8];
#pragma unroll
        for (int j = 0; j < 4; ++j)
            bfr[j] = *(const bf16x8*)&lB[(wc * 64 + j * 16 + lm) * 32 + q * 8];
#pragma unroll
        for (int i = 0; i < 4; ++i)
#pragma unroll
            for (int j = 0; j < 4; ++j)
                acc[i][j] = __builtin_amdgcn_mfma_f32_16x16x32_bf16(
                    af[i], bfr[j], acc[i][j], 0, 0, 0);
        __syncthreads();
    }

#pragma unroll
    for (int j = 0; j < 4; ++j) {
        const int col = n0 + wc * 64 + j * 16 + lm;
        const float bv = bias[col];
#pragma unroll
        for (int i = 0; i < 4; ++i) {
            const int row = m0 + wr * 64 + i * 16 + q * 4;
#pragma unroll
            for (int r = 0; r < 4; ++r)
                C[(size_t)(row + r) * N_DIM + col] = acc[i][j][r] + bv;
        }
    }
}

extern "C" void kernel_launch(void* const* d_in, const int* in_sizes, int n_in,
                              void* d_out, int out_size, void* d_ws, size_t ws_size,
                              hipStream_t stream) {
    const float* x = (const float*)d_in[0];
    const float* hw = (const float*)d_in[1];
    const void* rn = d_in[2];
    const float* bias = (const float*)d_in[3];
    float* out = (float*)d_out;

    const size_t wt_bytes = (size_t)N_DIM * K_DIM * 2;  // 32 MB
    const size_t xb_bytes = (size_t)M_DIM * K_DIM * 2;  // 64 MB

    if (ws_size >= wt_bytes + xb_bytes) {
        unsigned short* Wt = (unsigned short*)d_ws;
        unsigned short* Xb = (unsigned short*)((char*)d_ws + wt_bytes);
        build_wt<<<N_DIM, 256, 0, stream>>>(hw, rn, Wt);
        cvt_x<<<(M_DIM * K_DIM) / (8 * 256), 256, 0, stream>>>(x, Xb);
        gemm_bt8<<<dim3((M_DIM / 256) * (N_DIM / 256)), 512, 0, stream>>>(Xb, Wt, bias, out);
    } else {
        gemm_fused<<<dim3(N_DIM / 128, M_DIM / 128), 256, 0, stream>>>(x, hw, rn, bias, out);
    }
}